// Round 20
// baseline (76.363 us; speedup 1.0000x reference)
//
#include <hip/hip_runtime.h>

#define D      64
#define K      512
#define Q_OFF  0            // out[0 .. 8388607]   quantized_ste (NCHW)
#define L_OFF  8388608      // out[8388608]        commitment loss
#define I_OFF  8388609      // out[8388609 .. ]    indices (131072)

// ws layout (floats)
#define WS_ET    0          // 512*64 transposed embeddings (fp32, exact)
#define WS_EN    32768      // 512 ||e||^2 (exact, for recheck)
#define WS_ENH   33280      // 512 0.5*||e_rounded||^2 (for selection)
#define WS_PART  33792      // 4096 partial loss sums
#define WS_BH    40960      // hi B-fragment table, 16384 floats (64 KB)

// packed fixed-point selection constants
#define SEL_SCALE 16384.0f              // 2^14: resolution 6.1e-5
#define SEL_BIAS  (160.0f * 16384.0f)   // acc positive, < 2^23

typedef __attribute__((ext_vector_type(8))) short short8;   // 8 bf16 = 4 VGPRs
typedef __attribute__((ext_vector_type(4))) float f32x4;

static __device__ __forceinline__ unsigned short f2bf(float f) {
    unsigned u = __float_as_uint(f);
    u += 0x7fffu + ((u >> 16) & 1u);       // RTN-even
    return (unsigned short)(u >> 16);
}
static __device__ __forceinline__ float bf2f(unsigned short h) {
    return __uint_as_float(((unsigned)h) << 16);
}

// async global->LDS, 16 B per lane, linear layout
__device__ __forceinline__ void gload_lds16(const float* g, float* l) {
    __builtin_amdgcn_global_load_lds(
        (const __attribute__((address_space(1))) unsigned int*)g,
        (__attribute__((address_space(3))) unsigned int*)l, 16, 0, 0);
}

// ---------------------------------------------------------------- prep ----
// B-fragments: hi bf16 of (-e) only (2-pass scheme; e-rounding folded into
// ENH = 0.5*||bf16(e)||^2). EN stays exact for the recheck.
__global__ __launch_bounds__(256) void vq_prep(const float* __restrict__ E,
                                               float* __restrict__ ws) {
    int g = blockIdx.x * 256 + threadIdx.x;   // 0..2047 = (t, lane)
    int t = g >> 6, lane = g & 63;
    int col = lane & 15, kg = lane >> 4;
    int code = t * 16 + col;
    short8* bhp = (short8*)(ws + WS_BH);
#pragma unroll
    for (int s = 0; s < 2; ++s) {
        short8 h;
#pragma unroll
        for (int j = 0; j < 8; ++j) {
            int k = s * 32 + kg * 8 + j;
            h[j] = (short)f2bf(-E[k * K + code]);
        }
        bhp[(t * 2 + s) * 64 + lane] = h;
    }
    if (g < K) {
        float nsq = 0.f, nsqr = 0.f;
#pragma unroll 8
        for (int d = 0; d < D; ++d) {
            float v = E[d * K + g];
            ws[WS_ET + g * D + d] = v;
            nsq = fmaf(v, v, nsq);
            float vr = bf2f(f2bf(v));          // rounded codebook value
            nsqr = fmaf(vr, vr, nsqr);
        }
        ws[WS_EN + g]  = nsq;                  // exact (recheck)
        ws[WS_ENH + g] = 0.5f * nsqr;          // rounded (selection)
    }
}

// --------------------------------------------------------------- fused ----
// 4096 blocks x 2 waves; wave owns 16 pixels x 512 codes. 2-pass MFMA
// (x hi+lo vs rounded e), 2-code-tile chunks (4 KB, double-buffered),
// packed fixed-point TOP-4 selection vs rounded codebook, exact fp32
// recheck of all 4 candidates in the fused epilogue (4 threads/pixel,
// r13-proven coalesced layout). sdot overlaid on dead sbuf.
__device__ __forceinline__ float dot16(const float* __restrict__ er,
                                       const float* __restrict__ xv) {
    const float4* e4 = (const float4*)er;
    float a0 = 0.f, a1 = 0.f, a2 = 0.f, a3 = 0.f;
#pragma unroll
    for (int q = 0; q < 4; ++q) {
        float4 e = e4[q];
        a0 = fmaf(xv[4*q+0], e.x, a0);
        a1 = fmaf(xv[4*q+1], e.y, a1);
        a2 = fmaf(xv[4*q+2], e.z, a2);
        a3 = fmaf(xv[4*q+3], e.w, a3);
    }
    return (a0 + a1) + (a2 + a3);
}

__global__ __launch_bounds__(128, 8) void vq_fused(const float* __restrict__ x,
                                                   float* __restrict__ ws,
                                                   float* __restrict__ out,
                                                   float* __restrict__ partial) {
    __shared__ __align__(16) float sbuf[2][1024];  // 2 x 4 KB (2 code-tiles each)
    __shared__ uint2 sc2[32];                      // 4 candidates per pixel
    __shared__ float wsum2[2];

    const int tid = threadIdx.x, w = tid >> 6, lane = tid & 63;
    const int col = lane & 15, rowg = lane >> 4;
    const int pixw = blockIdx.x * 32 + w * 16;

    const float* bh    = ws + WS_BH;
    const float* enh_g = ws + WS_ENH;

    // stage chunk 0 (code-tiles 0,1)
    gload_lds16(bh + tid * 4,       sbuf[0] + tid * 4);
    gload_lds16(bh + 512 + tid * 4, sbuf[0] + 512 + tid * 4);

    // ---- load x fragment and split to bf16 hi/lo: A[s]
    short8 ah[2], al[2];
    {
        int pix = pixw + col;
        const float* xp = x + ((size_t)(pix >> 12) << 18) + (pix & 4095);
#pragma unroll
        for (int s = 0; s < 2; ++s) {
            short8 h, l;
#pragma unroll
            for (int j = 0; j < 8; ++j) {
                float v = xp[(size_t)(s * 32 + rowg * 8 + j) << 12];
                unsigned short hb = f2bf(v);
                h[j] = (short)hb;
                l[j] = (short)f2bf(v - bf2f(hb));
            }
            ah[s] = h; al[s] = l;
        }
    }

    unsigned m1[4], m2[4], m3[4], m4[4];
#pragma unroll
    for (int r = 0; r < 4; ++r) { m1[r]=~0u; m2[r]=~0u; m3[r]=~0u; m4[r]=~0u; }

    __syncthreads();                           // chunk 0 staged

    for (int c = 0; c < 16; ++c) {
        // prefetch chunk c+1 (2 tiles) into the other buffer
        if (c + 1 < 16) {
            const float* sh = bh + (c + 1) * 1024;
            float* db = sbuf[(c + 1) & 1];
            gload_lds16(sh + tid * 4,       db + tid * 4);
            gload_lds16(sh + 512 + tid * 4, db + 512 + tid * 4);
        }

        const short8* sb = (const short8*)sbuf[c & 1];
#pragma unroll
        for (int p = 0; p < 2; ++p) {
            const int t = c * 2 + p;
            const float ev = enh_g[t * 16 + col];
            const unsigned codev = (unsigned)(t * 16 + col);

            short8 cbh0 = sb[p * 128 + lane];
            short8 cbh1 = sb[p * 128 + 64 + lane];

            f32x4 acc = { ev, ev, ev, ev };
            __builtin_amdgcn_s_setprio(1);
            acc = __builtin_amdgcn_mfma_f32_16x16x32_bf16(ah[0], cbh0, acc, 0, 0, 0);
            acc = __builtin_amdgcn_mfma_f32_16x16x32_bf16(al[0], cbh0, acc, 0, 0, 0);
            acc = __builtin_amdgcn_mfma_f32_16x16x32_bf16(ah[1], cbh1, acc, 0, 0, 0);
            acc = __builtin_amdgcn_mfma_f32_16x16x32_bf16(al[1], cbh1, acc, 0, 0, 0);
            __builtin_amdgcn_s_setprio(0);

            // packed top-4 insert (sorted m1<=m2<=m3<=m4; index in low 9 bits)
#pragma unroll
            for (int r = 0; r < 4; ++r) {
                unsigned p0 = (((unsigned)fmaf(acc[r], SEL_SCALE, SEL_BIAS)) << 9) + codev;
                m4[r] = min(m4[r], max(m3[r], p0));
                m3[r] = min(m3[r], max(m2[r], p0));
                m2[r] = min(m2[r], max(m1[r], p0));
                m1[r] = min(m1[r], p0);
            }
        }
        __syncthreads();   // stage c+1 landed; both waves done with buf (c&1)
    }

    // cross-lane top-4 merge (sorted-list butterfly over the 16 code-cols)
#pragma unroll
    for (int r = 0; r < 4; ++r) {
        unsigned v1 = m1[r], v2 = m2[r], v3 = m3[r], v4 = m4[r];
#pragma unroll
        for (int mm = 1; mm < 16; mm <<= 1) {
            unsigned o1 = (unsigned)__shfl_xor((int)v1, mm, 16);
            unsigned o2 = (unsigned)__shfl_xor((int)v2, mm, 16);
            unsigned o3 = (unsigned)__shfl_xor((int)v3, mm, 16);
            unsigned o4 = (unsigned)__shfl_xor((int)v4, mm, 16);
            unsigned z1 = min(v1, o1);
            unsigned z2 = min(min(v2, o2), max(v1, o1));
            unsigned z3 = min(min(v3, o3), min(max(v2, o1), max(v1, o2)));
            unsigned z4 = min(min(min(v4, o4), max(v2, o2)),
                              min(max(v3, o1), max(v1, o3)));
            v1 = z1; v2 = z2; v3 = z3; v4 = z4;
        }
        if (col == r)
            sc2[w * 16 + rowg * 4 + r] =
                make_uint2((v1 & 511u) | ((v2 & 511u) << 16),
                           (v3 & 511u) | ((v4 & 511u) << 16));
    }
    __syncthreads();

    // ---------------- epilogue: 4 threads/pixel, exact recheck of 4 -------
    const float* ET = ws + WS_ET;
    const float* EN = ws + WS_EN;
    const int pl   = tid & 31;                // pixel-in-block
    const int part = tid >> 5;                // d-quarter 0..3
    const int n    = blockIdx.x * 32 + pl;    // global pixel
    const int b    = n >> 12;
    const int hw   = n & 4095;

    uint2 pk = sc2[pl];
    int c1 = (int)(pk.x & 0xffffu), c2 = (int)(pk.x >> 16);
    int c3 = (int)(pk.y & 0xffffu), c4 = (int)(pk.y >> 16);

    const float* xp2 = x + ((size_t)b << 18) + ((size_t)part << 16) + hw;
    float xv2[16];
#pragma unroll
    for (int d = 0; d < 16; ++d) xv2[d] = xp2[(size_t)d << 12];   // cache-resident

    float dp1 = dot16(ET + (c1 << 6) + part * 16, xv2);
    float dp2 = dot16(ET + (c2 << 6) + part * 16, xv2);
    float dp3 = dot16(ET + (c3 << 6) + part * 16, xv2);
    float dp4 = dot16(ET + (c4 << 6) + part * 16, xv2);
    float4* sdot4 = (float4*)&sbuf[0][0];     // sbuf dead after main loop
    sdot4[part * 32 + pl] = make_float4(dp1, dp2, dp3, dp4);
    __syncthreads();
    float4 q0 = sdot4[pl], q1 = sdot4[32 + pl], q2 = sdot4[64 + pl], q3 = sdot4[96 + pl];
    float d1 = fmaf(-2.f, (q0.x + q1.x) + (q2.x + q3.x), EN[c1]);
    float d2 = fmaf(-2.f, (q0.y + q1.y) + (q2.y + q3.y), EN[c2]);
    float d3 = fmaf(-2.f, (q0.z + q1.z) + (q2.z + q3.z), EN[c3]);
    float d4 = fmaf(-2.f, (q0.w + q1.w) + (q2.w + q3.w), EN[c4]);

    // np.argmin semantics: strict min, tie -> lowest index
    float db_ = d1; int cb_ = c1;
    if (d2 < db_ || (d2 == db_ && c2 < cb_)) { db_ = d2; cb_ = c2; }
    if (d3 < db_ || (d3 == db_ && c3 < cb_)) { db_ = d3; cb_ = c3; }
    if (d4 < db_ || (d4 == db_ && c4 < cb_)) { db_ = d4; cb_ = c4; }
    int bestk = cb_;

    if (part == 0) out[I_OFF + n] = (float)bestk;

    const float* qv = ET + (bestk << 6) + part * 16;
    float* op = out + Q_OFF + ((size_t)b << 18) + ((size_t)part << 16) + hw;
    float lsum = 0.f;
#pragma unroll
    for (int d = 0; d < 16; ++d) {
        float qd = qv[d];
        op[(size_t)d << 12] = qd;
        float diff = xv2[d] - qd;
        lsum = fmaf(diff, diff, lsum);
    }

    // deterministic block reduction of the loss (2 waves)
#pragma unroll
    for (int off = 32; off > 0; off >>= 1)
        lsum += __shfl_down(lsum, off, 64);
    if ((tid & 63) == 0) wsum2[tid >> 6] = lsum;
    __syncthreads();
    if (tid == 0)
        partial[blockIdx.x] = wsum2[0] + wsum2[1];
}

// --------------------------------------------------------------- final ----
__global__ __launch_bounds__(256) void vq_final(const float* __restrict__ partial,
                                                float* __restrict__ out) {
    int t = threadIdx.x;
    float s = 0.f;
#pragma unroll
    for (int i = 0; i < 16; ++i) s += partial[t + 256 * i];   // 4096 partials
#pragma unroll
    for (int off = 32; off > 0; off >>= 1)
        s += __shfl_down(s, off, 64);
    __shared__ float wsum[4];
    if ((t & 63) == 0) wsum[t >> 6] = s;
    __syncthreads();
    if (t == 0)
        out[L_OFF] = ((wsum[0] + wsum[1]) + (wsum[2] + wsum[3])) * (1.f / 8388608.f);
}

extern "C" void kernel_launch(void* const* d_in, const int* in_sizes, int n_in,
                              void* d_out, int out_size, void* d_ws, size_t ws_size,
                              hipStream_t stream) {
    const float* x = (const float*)d_in[0];
    const float* E = (const float*)d_in[1];
    float* out = (float*)d_out;
    float* ws  = (float*)d_ws;

    hipLaunchKernelGGL(vq_prep,  dim3(8),    dim3(256), 0, stream, E, ws);
    hipLaunchKernelGGL(vq_fused, dim3(4096), dim3(128), 0, stream, x, ws, out, ws + WS_PART);
    hipLaunchKernelGGL(vq_final, dim3(1),    dim3(256), 0, stream, ws + WS_PART, out);
}

// Round 21
// 61.643 us; speedup vs baseline: 1.2388x; 1.2388x over previous
//
#include <hip/hip_runtime.h>

#define D      64
#define K      512
#define Q_OFF  0            // out[0 .. 8388607]   quantized_ste (NCHW)
#define L_OFF  8388608      // out[8388608]        commitment loss
#define I_OFF  8388609      // out[8388609 .. ]    indices (131072)

// ws layout (floats)
#define WS_ET    0          // 512*64 transposed embeddings (fp32, exact)
#define WS_EN    32768      // 512 ||e||^2
#define WS_ENH   33280      // 512 0.5*||e||^2
#define WS_PART  33792      // 4096 partial loss sums
#define WS_BH    40960      // hi B-fragment table, 16384 floats (64 KB)
#define WS_BL    57344      // lo B-fragment table, 16384 floats (64 KB)

// packed fixed-point selection constants
#define SEL_SCALE 16384.0f              // 2^14: resolution 6.1e-5
#define SEL_BIAS  (160.0f * 16384.0f)   // acc positive, < 2^23

typedef __attribute__((ext_vector_type(8))) short short8;   // 8 bf16 = 4 VGPRs
typedef __attribute__((ext_vector_type(4))) float f32x4;

static __device__ __forceinline__ unsigned short f2bf(float f) {
    unsigned u = __float_as_uint(f);
    u += 0x7fffu + ((u >> 16) & 1u);       // RTN-even
    return (unsigned short)(u >> 16);
}
static __device__ __forceinline__ float bf2f(unsigned short h) {
    return __uint_as_float(((unsigned)h) << 16);
}

// async global->LDS, 16 B per lane, linear layout (lds dest: wave base + lane*16)
__device__ __forceinline__ void gload_lds16(const float* g, float* l) {
    __builtin_amdgcn_global_load_lds(
        (const __attribute__((address_space(1))) unsigned int*)g,
        (__attribute__((address_space(3))) unsigned int*)l, 16, 0, 0);
}

// ---------------------------------------------------------------- prep ----
__global__ __launch_bounds__(256) void vq_prep(const float* __restrict__ E,
                                               float* __restrict__ ws) {
    int g = blockIdx.x * 256 + threadIdx.x;   // 0..2047 = (t, lane)
    int t = g >> 6, lane = g & 63;
    int col = lane & 15, kg = lane >> 4;
    int code = t * 16 + col;
    short8* bhp = (short8*)(ws + WS_BH);
    short8* blp = (short8*)(ws + WS_BL);
#pragma unroll
    for (int s = 0; s < 2; ++s) {
        short8 h, l;
#pragma unroll
        for (int j = 0; j < 8; ++j) {
            int k = s * 32 + kg * 8 + j;
            float v = -E[k * K + code];
            unsigned short hb = f2bf(v);
            h[j] = (short)hb;
            l[j] = (short)f2bf(v - bf2f(hb));
        }
        bhp[(t * 2 + s) * 64 + lane] = h;
        blp[(t * 2 + s) * 64 + lane] = l;
    }
    if (g < K) {
        float nsq = 0.f;
#pragma unroll 8
        for (int d = 0; d < D; ++d) {
            float v = E[d * K + g];
            ws[WS_ET + g * D + d] = v;
            nsq = fmaf(v, v, nsq);
        }
        ws[WS_EN + g]  = nsq;
        ws[WS_ENH + g] = 0.5f * nsq;
    }
}

// --------------------------------------------------------------- fused ----
// Session-best configuration (61.3/61.7 us, reproduced): 4096 blocks x 2
// waves, wave owns 16 pixels (1 M-tile) x 512 codes; 16 blocks/CU = 8
// waves/SIMD. Single-tile chunks (4 KB), double-buffered gload_lds staging,
// 3-pass split-bf16 MFMA (selection error ~3e-5), packed fixed-point top-2
// (first-min-wins = np.argmin), fused exact-fp32-recheck epilogue at
// 4 threads/pixel — the unique layout where x-reads, e-gathers and q-writes
// are all coalesced (octet/register/issue-early/top-4 variants all
// regressed via memory-system side effects).
__device__ __forceinline__ float dot16(const float* __restrict__ er,
                                       const float* __restrict__ xv) {
    const float4* e4 = (const float4*)er;
    float a0 = 0.f, a1 = 0.f, a2 = 0.f, a3 = 0.f;
#pragma unroll
    for (int q = 0; q < 4; ++q) {
        float4 e = e4[q];
        a0 = fmaf(xv[4*q+0], e.x, a0);
        a1 = fmaf(xv[4*q+1], e.y, a1);
        a2 = fmaf(xv[4*q+2], e.z, a2);
        a3 = fmaf(xv[4*q+3], e.w, a3);
    }
    return (a0 + a1) + (a2 + a3);
}

__global__ __launch_bounds__(128, 8) void vq_fused(const float* __restrict__ x,
                                                   float* __restrict__ ws,
                                                   float* __restrict__ out,
                                                   float* __restrict__ partial) {
    __shared__ float sbuf[2][1024];           // 2 x 4 KB: hi [0,512), lo [512,1024)
    __shared__ unsigned sc[32];               // candidate pairs per pixel
    __shared__ float2 sdot[4][32];            // quarter-dot exchange
    __shared__ float wsum[2];

    const int tid = threadIdx.x, w = tid >> 6, lane = tid & 63;
    const int col = lane & 15, rowg = lane >> 4;
    const int pixw = blockIdx.x * 32 + w * 16;

    const float* bh    = ws + WS_BH;          // hi table (512 f/tile)
    const float* bl    = ws + WS_BL;          // lo table
    const float* enh_g = ws + WS_ENH;

    // stage chunk 0 into buffer 0
    gload_lds16(bh + tid * 4, sbuf[0] + tid * 4);
    gload_lds16(bl + tid * 4, sbuf[0] + 512 + tid * 4);

    // ---- load x fragment and split to bf16 hi/lo: A[s]
    short8 ah[2], al[2];
    {
        int pix = pixw + col;
        const float* xp = x + ((size_t)(pix >> 12) << 18) + (pix & 4095);
#pragma unroll
        for (int s = 0; s < 2; ++s) {
            short8 h, l;
#pragma unroll
            for (int j = 0; j < 8; ++j) {
                float v = xp[(size_t)(s * 32 + rowg * 8 + j) << 12];
                unsigned short hb = f2bf(v);
                h[j] = (short)hb;
                l[j] = (short)f2bf(v - bf2f(hb));
            }
            ah[s] = h; al[s] = l;
        }
    }

    unsigned m1[4], m2[4];
#pragma unroll
    for (int r = 0; r < 4; ++r) { m1[r] = 0xFFFFFFFFu; m2[r] = 0xFFFFFFFFu; }

    __syncthreads();                           // chunk 0 staged

    for (int c = 0; c < 32; ++c) {
        // prefetch chunk c+1 into the other buffer
        if (c + 1 < 32) {
            const float* sh = bh + (c + 1) * 512;
            const float* sl = bl + (c + 1) * 512;
            float* db = sbuf[(c + 1) & 1];
            gload_lds16(sh + tid * 4, db + tid * 4);
            gload_lds16(sl + tid * 4, db + 512 + tid * 4);
        }

        const short8* sb = (const short8*)sbuf[c & 1];
        const float ev = enh_g[c * 16 + col];  // L1-hot 2KB table
        const unsigned codev = (unsigned)(c * 16 + col);

        short8 cbh0 = sb[lane];
        short8 cbh1 = sb[64 + lane];
        short8 cbl0 = sb[128 + lane];
        short8 cbl1 = sb[192 + lane];

        f32x4 acc = { ev, ev, ev, ev };
        __builtin_amdgcn_s_setprio(1);
        acc = __builtin_amdgcn_mfma_f32_16x16x32_bf16(ah[0], cbh0, acc, 0, 0, 0);
        acc = __builtin_amdgcn_mfma_f32_16x16x32_bf16(al[0], cbh0, acc, 0, 0, 0);
        acc = __builtin_amdgcn_mfma_f32_16x16x32_bf16(ah[0], cbl0, acc, 0, 0, 0);
        acc = __builtin_amdgcn_mfma_f32_16x16x32_bf16(ah[1], cbh1, acc, 0, 0, 0);
        acc = __builtin_amdgcn_mfma_f32_16x16x32_bf16(al[1], cbh1, acc, 0, 0, 0);
        acc = __builtin_amdgcn_mfma_f32_16x16x32_bf16(ah[1], cbl1, acc, 0, 0, 0);
        __builtin_amdgcn_s_setprio(0);

        // packed top-2 update: 6 VALU per acc element
#pragma unroll
        for (int r = 0; r < 4; ++r) {
            unsigned p0 = (((unsigned)fmaf(acc[r], SEL_SCALE, SEL_BIAS)) << 9) + codev;
            m2[r] = min(m2[r], max(m1[r], p0));
            m1[r] = min(m1[r], p0);
        }

        __syncthreads();   // stage c+1 landed; both waves done with buf (c&1)
    }

    // cross-lane top-2 merge over the 16 code-columns; park pairs in LDS
#pragma unroll
    for (int r = 0; r < 4; ++r) {
        unsigned v1 = m1[r], v2 = m2[r];
#pragma unroll
        for (int m = 1; m < 16; m <<= 1) {
            unsigned o1 = (unsigned)__shfl_xor((int)v1, m, 16);
            unsigned o2 = (unsigned)__shfl_xor((int)v2, m, 16);
            v2 = min(max(v1, o1), min(v2, o2));
            v1 = min(v1, o1);
        }
        if (col == r)
            sc[w * 16 + rowg * 4 + r] = (v1 & 511u) | ((v2 & 511u) << 16);
    }
    __syncthreads();

    // ---------------- fused epilogue: 4 threads per pixel (d-quarters) ----
    const float* ET = ws + WS_ET;
    const float* EN = ws + WS_EN;
    const int pl   = tid & 31;                // pixel-in-block
    const int part = tid >> 5;                // d-quarter 0..3
    const int n    = blockIdx.x * 32 + pl;    // global pixel
    const int b    = n >> 12;
    const int hw   = n & 4095;

    unsigned pk = sc[pl];
    int c1 = (int)(pk & 0xffffu), c2 = (int)(pk >> 16);

    const float* xp2 = x + ((size_t)b << 18) + ((size_t)part << 16) + hw;
    float xv2[16];
#pragma unroll
    for (int d = 0; d < 16; ++d) xv2[d] = xp2[(size_t)d << 12];   // cache-resident

    float dp1 = dot16(ET + (c1 << 6) + part * 16, xv2);
    float dp2 = dot16(ET + (c2 << 6) + part * 16, xv2);
    sdot[part][pl] = make_float2(dp1, dp2);
    __syncthreads();
    float2 q0 = sdot[0][pl], q1 = sdot[1][pl], q2 = sdot[2][pl], q3 = sdot[3][pl];
    float d1 = fmaf(-2.f, (q0.x + q1.x) + (q2.x + q3.x), EN[c1]);
    float d2 = fmaf(-2.f, (q0.y + q1.y) + (q2.y + q3.y), EN[c2]);
    bool sw = (d2 < d1) || (d2 == d1 && c2 < c1);   // np.argmin: first min wins
    int bestk = sw ? c2 : c1;

    if (part == 0) out[I_OFF + n] = (float)bestk;

    const float* qv = ET + (bestk << 6) + part * 16;
    float* op = out + Q_OFF + ((size_t)b << 18) + ((size_t)part << 16) + hw;
    float lsum = 0.f;
#pragma unroll
    for (int d = 0; d < 16; ++d) {
        float qd = qv[d];
        op[(size_t)d << 12] = qd;
        float diff = xv2[d] - qd;
        lsum = fmaf(diff, diff, lsum);
    }

    // deterministic block reduction of the loss (2 waves)
#pragma unroll
    for (int off = 32; off > 0; off >>= 1)
        lsum += __shfl_down(lsum, off, 64);
    if ((tid & 63) == 0) wsum[tid >> 6] = lsum;
    __syncthreads();
    if (tid == 0)
        partial[blockIdx.x] = wsum[0] + wsum[1];
}

// --------------------------------------------------------------- final ----
__global__ __launch_bounds__(256) void vq_final(const float* __restrict__ partial,
                                                float* __restrict__ out) {
    int t = threadIdx.x;
    float s = 0.f;
#pragma unroll
    for (int i = 0; i < 16; ++i) s += partial[t + 256 * i];   // 4096 partials
#pragma unroll
    for (int off = 32; off > 0; off >>= 1)
        s += __shfl_down(s, off, 64);
    __shared__ float wsum[4];
    if ((t & 63) == 0) wsum[t >> 6] = s;
    __syncthreads();
    if (t == 0)
        out[L_OFF] = ((wsum[0] + wsum[1]) + (wsum[2] + wsum[3])) * (1.f / 8388608.f);
}

extern "C" void kernel_launch(void* const* d_in, const int* in_sizes, int n_in,
                              void* d_out, int out_size, void* d_ws, size_t ws_size,
                              hipStream_t stream) {
    const float* x = (const float*)d_in[0];
    const float* E = (const float*)d_in[1];
    float* out = (float*)d_out;
    float* ws  = (float*)d_ws;

    hipLaunchKernelGGL(vq_prep,  dim3(8),    dim3(256), 0, stream, E, ws);
    hipLaunchKernelGGL(vq_fused, dim3(4096), dim3(128), 0, stream, x, ws, out, ws + WS_PART);
    hipLaunchKernelGGL(vq_final, dim3(1),    dim3(256), 0, stream, ws + WS_PART, out);
}